// Round 3
// baseline (2187.497 us; speedup 1.0000x reference)
//
#include <hip/hip_runtime.h>
#include <math.h>

#define NN 100000
#define CC 64
#define EPSF 1e-8f
#define LOG_C 4.1588830833596715f

__device__ __forceinline__ float waveSum(float v) {
#pragma unroll
    for (int off = 32; off; off >>= 1) v += __shfl_xor(v, off);
    return v;
}
__device__ __forceinline__ float waveMax(float v) {
#pragma unroll
    for (int off = 32; off; off >>= 1) v = fmaxf(v, __shfl_xor(v, off));
    return v;
}
__device__ __forceinline__ int waveMinI(int v) {
#pragma unroll
    for (int off = 32; off; off >>= 1) v = min(v, __shfl_xor(v, off));
    return v;
}
__device__ __forceinline__ float clip01(float v) { return fminf(fmaxf(v, 0.f), 1.f); }
__device__ __forceinline__ float sigmoidf(float x) { return 1.f / (1.f + expf(-x)); }

// K1: seed=relu(logits), per-row mass/certainty; accumulate sum(mass), sum(clustering)
__global__ void k_seed(const float* __restrict__ logits, const float* __restrict__ sf,
                       float* __restrict__ seed, float* __restrict__ prop,
                       float* __restrict__ mass, float* __restrict__ cert,
                       float* __restrict__ scal) {
    int lane = threadIdx.x & 63;
    int wid = threadIdx.x >> 6;
    float accm = 0.f, accc = 0.f;
    for (int row = blockIdx.x * 4 + wid; row < NN; row += gridDim.x * 4) {
        float l = logits[row * CC + lane];
        float s = fmaxf(l, 0.f);
        seed[row * CC + lane] = s;
        prop[row * CC + lane] = s;
        float m = waveSum(s);
        float nrm = s / (m + EPSF);
        float ent = waveSum(-nrm * logf(nrm + EPSF));
        if (lane == 0) {
            mass[row] = m;
            cert[row] = 1.f - ent / LOG_C;
            accm += m;
            accc += sf[row * 2 + 1];
        }
    }
    __shared__ float sm[8];
    if (lane == 0) { sm[wid] = accm; sm[4 + wid] = accc; }
    __syncthreads();
    if (threadIdx.x == 0) {
        atomicAdd(&scal[0], sm[0] + sm[1] + sm[2] + sm[3]);
        atomicAdd(&scal[1], sm[4] + sm[5] + sm[6] + sm[7]);
    }
}

// K2: confidence, source_gate; accumulate global_prior numerator (64-vec) and sum(conf)
__global__ void k_conf(const float* __restrict__ seed, const float* __restrict__ mass,
                       const float* __restrict__ cert, float* __restrict__ conf,
                       float* __restrict__ sg, float* __restrict__ scal,
                       float* __restrict__ gp) {
    int lane = threadIdx.x & 63;
    int wid = threadIdx.x >> 6;
    float msc = fmaxf(scal[0] * (1.f / NN), EPSF);
    float accgp = 0.f, accconf = 0.f;
    for (int row = blockIdx.x * 4 + wid; row < NN; row += gridDim.x * 4) {
        float m = mass[row], ct = cert[row];
        float cf = clip01(0.5f * ct + 0.5f * tanhf(m / msc));
        accgp += cf * seed[row * CC + lane];
        if (lane == 0) {
            conf[row] = cf;
            sg[row] = sigmoidf(8.f * (cf - 0.55f));
            accconf += cf;
        }
    }
    __shared__ float sgp[256];
    __shared__ float scf[4];
    sgp[threadIdx.x] = accgp;
    if (lane == 0) scf[wid] = accconf;
    __syncthreads();
    if (threadIdx.x < 64)
        atomicAdd(&gp[lane], sgp[lane] + sgp[64 + lane] + sgp[128 + lane] + sgp[192 + lane]);
    if (threadIdx.x == 0) atomicAdd(&scal[2], scf[0] + scf[1] + scf[2] + scf[3]);
}

// K3: finalize global_prior and graph_scale
__global__ void k_finalize(float* __restrict__ scal, float* __restrict__ gp) {
    float sc = fmaxf(scal[2], EPSF);
    gp[threadIdx.x] = gp[threadIdx.x] / sc;
    if (threadIdx.x == 0) {
        scal[3] = fminf(fmaxf(1.f - scal[1] * (1.f / NN), 0.2f), 1.f);
    }
}

// SPMM over edges. MODE 0: out += w*x[src], den += w*sg[src]. MODE 1: out += w*sg[src]*x[src].
// MODE 2: out += w*x[src].
template <int MODE>
__global__ void k_spmm(const int* __restrict__ src, const int* __restrict__ dst,
                       const float* __restrict__ w, const float* __restrict__ x,
                       const float* __restrict__ sg, float* __restrict__ out,
                       float* __restrict__ den, int E) {
    int lane = threadIdx.x & 63;
    int wave = blockIdx.x * (blockDim.x >> 6) + (threadIdx.x >> 6);
    int base = wave * 64;
    if (base >= E) return;
    int e = base + lane;
    int s_ = 0, d_ = 0;
    float w_ = 0.f;
    if (e < E) { s_ = src[e]; d_ = dst[e]; w_ = w[e]; }
    int cnt = min(64, E - base);
    for (int i = 0; i < cnt; ++i) {
        int si = __shfl(s_, i);
        int di = __shfl(d_, i);
        float wi = __shfl(w_, i);
        float scale;
        if (MODE == 1) scale = wi * sg[si];
        else scale = wi;
        float v = x[si * CC + lane] * scale;
        atomicAdd(&out[di * CC + lane], v);
        if (MODE == 0 && lane == 0) atomicAdd(&den[di], wi * sg[si]);
    }
}

// quality(state, ctx, clustering) -> qout[row]
__global__ void k_quality(const float* __restrict__ state, const float* __restrict__ ctx,
                          const float* __restrict__ sf, float* __restrict__ qout) {
    int lane = threadIdx.x & 63;
    int wid = threadIdx.x >> 6;
    int row = blockIdx.x * 4 + wid;
    if (row >= NN) return;
    float s = state[row * CC + lane];
    float c = ctx[row * CC + lane];
    float dot = s * c, ss = s * s, cc = c * c, m = s;
#pragma unroll
    for (int off = 32; off; off >>= 1) {
        dot += __shfl_xor(dot, off);
        ss += __shfl_xor(ss, off);
        cc += __shfl_xor(cc, off);
        m += __shfl_xor(m, off);
    }
    float cosv = dot / (fmaxf(sqrtf(ss), 1e-8f) * fmaxf(sqrtf(cc), 1e-8f));
    float lq = clip01((cosv + 1.f) * 0.5f);
    float p = s / (m + EPSF);
    float m1 = waveMax(p);
    int idx = (p == m1) ? lane : 64;
    int first = waveMinI(idx);
    float p2 = (lane == first) ? -3.4e38f : p;
    float m2 = waveMax(p2);
    float margin = m1 - m2;
    if (lane == 0) {
        qout[row] = 0.7f * lq + 0.2f * margin + 0.1f * sf[row * 2 + 1];
    }
}

// one propagation update step
__global__ void k_update(const float* __restrict__ num, const float* __restrict__ den,
                         const float* __restrict__ gp, const float* __restrict__ conf,
                         const float* __restrict__ sf, const float* __restrict__ seed,
                         float* __restrict__ prop, const float* __restrict__ scal) {
    int lane = threadIdx.x & 63;
    int wid = threadIdx.x >> 6;
    int row = blockIdx.x * 4 + wid;
    if (row >= NN) return;
    float dn = fmaxf(den[row], EPSF);
    float f = 0.95f * (num[row * CC + lane] / dn) + 0.05f * gp[lane];
    float p = prop[row * CC + lane];
    float s = seed[row * CC + lane];
    float pf = p * f, pp = p * p, ff = f * f, sfv = s * f, ss = s * s;
#pragma unroll
    for (int off = 32; off; off >>= 1) {
        pf += __shfl_xor(pf, off);
        pp += __shfl_xor(pp, off);
        ff += __shfl_xor(ff, off);
        sfv += __shfl_xor(sfv, off);
        ss += __shfl_xor(ss, off);
    }
    float nf = fmaxf(sqrtf(ff), 1e-8f);
    float agree = clip01((pf / (fmaxf(sqrtf(pp), 1e-8f) * nf) + 1.f) * 0.5f);
    float sagree = clip01((sfv / (fmaxf(sqrtf(ss), 1e-8f) * nf) + 1.f) * 0.5f);
    float cf = conf[row];
    float anchor = fminf(fmaxf(0.6f + 0.2f * cf, 0.f), 0.995f);
    float unc = 1.f - cf;
    float lowdeg = clip01(1.f - sf[row * 2 + 0]);
    float lowcl = clip01(1.f - sf[row * 2 + 1]);
    float rec = sigmoidf(8.f * (0.5f - cf));
    float sel = clip01(unc + 0.25f * lowdeg + 0.2f * sagree + 0.2f * lowcl);
    float ug = rec * sel * agree * (1.f - anchor);
    float res = 0.15f * scal[3] * ug * (f - p);
    prop[row * CC + lane] = fmaxf(anchor * s + (1.f - anchor) * p + res, 0.f);
}

// final: prop quality, accept, blend -> out (out also holds prop_ctx; each thread
// reads its own ctx element before overwriting it — thread-private, safe)
__global__ void k_final(const float* __restrict__ prop, const float* __restrict__ seed,
                        const float* __restrict__ sf, const float* __restrict__ baseq,
                        float* __restrict__ outp) {
    int lane = threadIdx.x & 63;
    int wid = threadIdx.x >> 6;
    int row = blockIdx.x * 4 + wid;
    if (row >= NN) return;
    float s = prop[row * CC + lane];
    float c = outp[row * CC + lane];  // prop_ctx accumulated here
    float dot = s * c, ss = s * s, cc = c * c, m = s;
#pragma unroll
    for (int off = 32; off; off >>= 1) {
        dot += __shfl_xor(dot, off);
        ss += __shfl_xor(ss, off);
        cc += __shfl_xor(cc, off);
        m += __shfl_xor(m, off);
    }
    float cosv = dot / (fmaxf(sqrtf(ss), 1e-8f) * fmaxf(sqrtf(cc), 1e-8f));
    float lq = clip01((cosv + 1.f) * 0.5f);
    float p = s / (m + EPSF);
    float m1 = waveMax(p);
    int idx = (p == m1) ? lane : 64;
    int first = waveMinI(idx);
    float p2 = (lane == first) ? -3.4e38f : p;
    float m2 = waveMax(p2);
    float q = 0.7f * lq + 0.2f * (m1 - m2) + 0.1f * sf[row * 2 + 1];
    float acc = sigmoidf(12.f * (q - baseq[row]));
    float sd = seed[row * CC + lane];
    outp[row * CC + lane] = acc * s + (1.f - acc) * sd;
}

extern "C" void kernel_launch(void* const* d_in, const int* in_sizes, int n_in,
                              void* d_out, int out_size, void* d_ws, size_t ws_size,
                              hipStream_t stream) {
    const float* logits = (const float*)d_in[0];
    const float* ew = (const float*)d_in[1];
    const float* sf = (const float*)d_in[2];
    const int* esrc = (const int*)d_in[3];
    const int* edst = (const int*)d_in[4];
    float* out = (float*)d_out;
    int E = in_sizes[1];

    float* ws = (float*)d_ws;
    float* seed = ws;               // N*C
    float* prop = seed + NN * CC;   // N*C
    float* massA = prop + NN * CC;  // N
    float* certA = massA + NN;      // N
    float* confA = certA + NN;      // N
    float* sgA = confA + NN;        // N
    float* denA = sgA + NN;         // N
    float* bqA = denA + NN;         // N
    float* scal = bqA + NN;         // 8
    float* gp = scal + 8;           // 64
    float* num = out;               // reuse d_out as the SPMM accumulator

    hipMemsetAsync(scal, 0, (8 + 64) * sizeof(float), stream);

    const int redBlocks = 1024;
    const int rowBlocks = (NN + 3) / 4;
    const int edgeBlocks = (E + 255) / 256;

    k_seed<<<redBlocks, 256, 0, stream>>>(logits, sf, seed, prop, massA, certA, scal);
    k_conf<<<redBlocks, 256, 0, stream>>>(seed, massA, certA, confA, sgA, scal, gp);
    k_finalize<<<1, 64, 0, stream>>>(scal, gp);

    // base_ctx (seed) + local_den (source_gate), both constant across the loop
    hipMemsetAsync(num, 0, (size_t)NN * CC * sizeof(float), stream);
    hipMemsetAsync(denA, 0, NN * sizeof(float), stream);
    k_spmm<0><<<edgeBlocks, 256, 0, stream>>>(esrc, edst, ew, seed, sgA, num, denA, E);
    k_quality<<<rowBlocks, 256, 0, stream>>>(seed, num, sf, bqA);

    for (int t = 0; t < 3; ++t) {
        hipMemsetAsync(num, 0, (size_t)NN * CC * sizeof(float), stream);
        k_spmm<1><<<edgeBlocks, 256, 0, stream>>>(esrc, edst, ew, prop, sgA, num, nullptr, E);
        k_update<<<rowBlocks, 256, 0, stream>>>(num, denA, gp, confA, sf, seed, prop, scal);
    }

    hipMemsetAsync(num, 0, (size_t)NN * CC * sizeof(float), stream);
    k_spmm<2><<<edgeBlocks, 256, 0, stream>>>(esrc, edst, ew, prop, sgA, num, nullptr, E);
    k_final<<<rowBlocks, 256, 0, stream>>>(prop, seed, sf, bqA, out);
}

// Round 4
// 969.022 us; speedup vs baseline: 2.2574x; 2.2574x over previous
//
#include <hip/hip_runtime.h>
#include <math.h>

#define NN 100000
#define CC 64
#define EPSF 1e-8f
#define LOG_C 4.1588830833596715f
#define SCAN_BS 1024
#define NSB ((NN + SCAN_BS - 1) / SCAN_BS)

__device__ __forceinline__ float waveSum(float v) {
#pragma unroll
    for (int off = 32; off; off >>= 1) v += __shfl_xor(v, off);
    return v;
}
__device__ __forceinline__ float waveMax(float v) {
#pragma unroll
    for (int off = 32; off; off >>= 1) v = fmaxf(v, __shfl_xor(v, off));
    return v;
}
__device__ __forceinline__ int waveMinI(int v) {
#pragma unroll
    for (int off = 32; off; off >>= 1) v = min(v, __shfl_xor(v, off));
    return v;
}
__device__ __forceinline__ float clip01(float v) { return fminf(fmaxf(v, 0.f), 1.f); }
__device__ __forceinline__ float sigmoidf(float x) { return 1.f / (1.f + expf(-x)); }

// ---------------- row-wise prologue kernels (unchanged from validated baseline) ----

__global__ void k_seed(const float* __restrict__ logits, const float* __restrict__ sf,
                       float* __restrict__ seed, float* __restrict__ prop,
                       float* __restrict__ mass, float* __restrict__ cert,
                       float* __restrict__ scal) {
    int lane = threadIdx.x & 63;
    int wid = threadIdx.x >> 6;
    float accm = 0.f, accc = 0.f;
    for (int row = blockIdx.x * 4 + wid; row < NN; row += gridDim.x * 4) {
        float l = logits[row * CC + lane];
        float s = fmaxf(l, 0.f);
        seed[row * CC + lane] = s;
        prop[row * CC + lane] = s;
        float m = waveSum(s);
        float nrm = s / (m + EPSF);
        float ent = waveSum(-nrm * logf(nrm + EPSF));
        if (lane == 0) {
            mass[row] = m;
            cert[row] = 1.f - ent / LOG_C;
            accm += m;
            accc += sf[row * 2 + 1];
        }
    }
    __shared__ float sm[8];
    if (lane == 0) { sm[wid] = accm; sm[4 + wid] = accc; }
    __syncthreads();
    if (threadIdx.x == 0) {
        atomicAdd(&scal[0], sm[0] + sm[1] + sm[2] + sm[3]);
        atomicAdd(&scal[1], sm[4] + sm[5] + sm[6] + sm[7]);
    }
}

__global__ void k_conf(const float* __restrict__ seed, const float* __restrict__ mass,
                       const float* __restrict__ cert, float* __restrict__ conf,
                       float* __restrict__ sg, float* __restrict__ scal,
                       float* __restrict__ gp) {
    int lane = threadIdx.x & 63;
    int wid = threadIdx.x >> 6;
    float msc = fmaxf(scal[0] * (1.f / NN), EPSF);
    float accgp = 0.f, accconf = 0.f;
    for (int row = blockIdx.x * 4 + wid; row < NN; row += gridDim.x * 4) {
        float m = mass[row], ct = cert[row];
        float cf = clip01(0.5f * ct + 0.5f * tanhf(m / msc));
        accgp += cf * seed[row * CC + lane];
        if (lane == 0) {
            conf[row] = cf;
            sg[row] = sigmoidf(8.f * (cf - 0.55f));
            accconf += cf;
        }
    }
    __shared__ float sgp[256];
    __shared__ float scf[4];
    sgp[threadIdx.x] = accgp;
    if (lane == 0) scf[wid] = accconf;
    __syncthreads();
    if (threadIdx.x < 64)
        atomicAdd(&gp[lane], sgp[lane] + sgp[64 + lane] + sgp[128 + lane] + sgp[192 + lane]);
    if (threadIdx.x == 0) atomicAdd(&scal[2], scf[0] + scf[1] + scf[2] + scf[3]);
}

__global__ void k_finalize(float* __restrict__ scal, float* __restrict__ gp) {
    float sc = fmaxf(scal[2], EPSF);
    gp[threadIdx.x] = gp[threadIdx.x] / sc;
    if (threadIdx.x == 0) {
        scal[3] = fminf(fmaxf(1.f - scal[1] * (1.f / NN), 0.2f), 1.f);
    }
}

// ---------------- CSR build ----------------

__global__ void k_hist(const int* __restrict__ dst, int* __restrict__ count, int E) {
    int i = blockIdx.x * blockDim.x + threadIdx.x;
    int stride = gridDim.x * blockDim.x;
    for (; i < E; i += stride) atomicAdd(&count[dst[i]], 1);
}

__global__ void k_bsum(const int* __restrict__ count, int* __restrict__ bsum) {
    int b = blockIdx.x, t = threadIdx.x;
    int base = b * SCAN_BS + t * 4;
    int s = 0;
#pragma unroll
    for (int k = 0; k < 4; ++k) {
        int i = base + k;
        if (i < NN) s += count[i];
    }
#pragma unroll
    for (int off = 32; off; off >>= 1) s += __shfl_xor(s, off);
    __shared__ int red[4];
    if ((t & 63) == 0) red[t >> 6] = s;
    __syncthreads();
    if (t == 0) bsum[b] = red[0] + red[1] + red[2] + red[3];
}

__global__ void k_boff(const int* __restrict__ bsum, int* __restrict__ boff,
                       int* __restrict__ row_start) {
    int acc = 0;
    for (int i = 0; i < NSB; ++i) { boff[i] = acc; acc += bsum[i]; }
    row_start[NN] = acc;  // == E
}

__global__ void k_scanwrite(const int* __restrict__ count, const int* __restrict__ boff,
                            int* __restrict__ row_start, int* __restrict__ cursor) {
    int b = blockIdx.x, t = threadIdx.x, lane = t & 63, wid = t >> 6;
    int base = b * SCAN_BS + t * 4;
    int c0 = 0, c1 = 0, c2 = 0, c3 = 0;
    if (base < NN) c0 = count[base];
    if (base + 1 < NN) c1 = count[base + 1];
    if (base + 2 < NN) c2 = count[base + 2];
    if (base + 3 < NN) c3 = count[base + 3];
    int s = c0 + c1 + c2 + c3;
    int incl = s;
#pragma unroll
    for (int off = 1; off < 64; off <<= 1) {
        int o = __shfl_up(incl, off);
        if (lane >= off) incl += o;
    }
    __shared__ int wsum[4];
    if (lane == 63) wsum[wid] = incl;
    __syncthreads();
    int woff = 0;
    for (int i = 0; i < wid; ++i) woff += wsum[i];
    int excl = boff[b] + woff + incl - s;
    if (base < NN) { row_start[base] = excl; cursor[base] = excl; excl += c0; }
    if (base + 1 < NN) { row_start[base + 1] = excl; cursor[base + 1] = excl; excl += c1; }
    if (base + 2 < NN) { row_start[base + 2] = excl; cursor[base + 2] = excl; excl += c2; }
    if (base + 3 < NN) { row_start[base + 3] = excl; cursor[base + 3] = excl; excl += c3; }
}

__global__ void k_scatter(const int* __restrict__ src, const int* __restrict__ dst,
                          const float* __restrict__ w, int* __restrict__ cursor,
                          int2* __restrict__ edge_pk, int E) {
    int i = blockIdx.x * blockDim.x + threadIdx.x;
    int stride = gridDim.x * blockDim.x;
    for (; i < E; i += stride) {
        int d = dst[i];
        int pos = atomicAdd(&cursor[d], 1);
        edge_pk[pos] = make_int2(src[i], __float_as_int(w[i]));
    }
}

// ---------------- CSR SPMM, one wave per dst row (lane = channel) -----------
// MODE 0: acc = sum w*seed[src]; den[row] = sum w*sg[src]; epilogue: base quality -> bq
// MODE 1: acc = sum (w*sg[src])*prop[src]; write num[row] (coalesced, no atomics)
// MODE 2: acc = sum w*prop[src]; epilogue: prop quality + accept + blend -> out

template <int MODE>
__global__ __launch_bounds__(256) void k_csr(
    const int2* __restrict__ edge_pk, const int* __restrict__ row_start,
    const float* __restrict__ x, const float* __restrict__ sg,
    const float* __restrict__ seed, const float* __restrict__ sf,
    float* __restrict__ den, float* __restrict__ bq,
    float* __restrict__ numo, const float* __restrict__ baseq,
    float* __restrict__ outp) {
    int lane = threadIdx.x & 63;
    int row = blockIdx.x * 4 + (threadIdx.x >> 6);
    if (row >= NN) return;
    int rs = row_start[row], re = row_start[row + 1];
    float acc = 0.f, accden = 0.f;
    for (int base = rs; base < re; base += 64) {
        int e = base + lane;
        int s_ = 0;
        float w_ = 0.f;
        if (e < re) {
            int2 pk = edge_pk[e];
            s_ = pk.x;
            w_ = __int_as_float(pk.y);
        }
        float wm_ = w_;
        if (MODE == 0) accden += (e < re) ? w_ * sg[s_] : 0.f;
        if (MODE == 1) wm_ = (e < re) ? w_ * sg[s_] : 0.f;
        int cnt = min(64, re - base);
        for (int i = 0; i < cnt; ++i) {
            int si = __shfl(s_, i);
            float wi = __shfl(wm_, i);
            acc += wi * x[si * CC + lane];
        }
    }

    if (MODE == 1) {
        numo[row * CC + lane] = acc;
        return;
    }

    // quality epilogue (MODE 0 on seed, MODE 2 on prop=x's own row)
    float s = (MODE == 0) ? seed[row * CC + lane] : x[row * CC + lane];
    float c = acc;
    float dot = s * c, ss = s * s, cc2 = c * c, m = s;
#pragma unroll
    for (int off = 32; off; off >>= 1) {
        dot += __shfl_xor(dot, off);
        ss += __shfl_xor(ss, off);
        cc2 += __shfl_xor(cc2, off);
        m += __shfl_xor(m, off);
    }
    float cosv = dot / (fmaxf(sqrtf(ss), 1e-8f) * fmaxf(sqrtf(cc2), 1e-8f));
    float lq = clip01((cosv + 1.f) * 0.5f);
    float p = s / (m + EPSF);
    float m1 = waveMax(p);
    int idx = (p == m1) ? lane : 64;
    int first = waveMinI(idx);
    float p2 = (lane == first) ? -3.4e38f : p;
    float m2 = waveMax(p2);
    float q = 0.7f * lq + 0.2f * (m1 - m2) + 0.1f * sf[row * 2 + 1];

    if (MODE == 0) {
        float dsum = waveSum(accden);
        if (lane == 0) {
            den[row] = dsum;
            bq[row] = q;
        }
    } else {  // MODE 2: accept + blend
        float accp = sigmoidf(12.f * (q - baseq[row]));
        float sd = seed[row * CC + lane];
        outp[row * CC + lane] = accp * s + (1.f - accp) * sd;
    }
}

// ---------------- propagation update (separate: gathers must see old prop) ---

__global__ void k_update(const float* __restrict__ num, const float* __restrict__ den,
                         const float* __restrict__ gp, const float* __restrict__ conf,
                         const float* __restrict__ sf, const float* __restrict__ seed,
                         float* __restrict__ prop, const float* __restrict__ scal) {
    int lane = threadIdx.x & 63;
    int wid = threadIdx.x >> 6;
    int row = blockIdx.x * 4 + wid;
    if (row >= NN) return;
    float dn = fmaxf(den[row], EPSF);
    float f = 0.95f * (num[row * CC + lane] / dn) + 0.05f * gp[lane];
    float p = prop[row * CC + lane];
    float s = seed[row * CC + lane];
    float pf = p * f, pp = p * p, ff = f * f, sfv = s * f, ss = s * s;
#pragma unroll
    for (int off = 32; off; off >>= 1) {
        pf += __shfl_xor(pf, off);
        pp += __shfl_xor(pp, off);
        ff += __shfl_xor(ff, off);
        sfv += __shfl_xor(sfv, off);
        ss += __shfl_xor(ss, off);
    }
    float nf = fmaxf(sqrtf(ff), 1e-8f);
    float agree = clip01((pf / (fmaxf(sqrtf(pp), 1e-8f) * nf) + 1.f) * 0.5f);
    float sagree = clip01((sfv / (fmaxf(sqrtf(ss), 1e-8f) * nf) + 1.f) * 0.5f);
    float cf = conf[row];
    float anchor = fminf(fmaxf(0.6f + 0.2f * cf, 0.f), 0.995f);
    float unc = 1.f - cf;
    float lowdeg = clip01(1.f - sf[row * 2 + 0]);
    float lowcl = clip01(1.f - sf[row * 2 + 1]);
    float rec = sigmoidf(8.f * (0.5f - cf));
    float sel = clip01(unc + 0.25f * lowdeg + 0.2f * sagree + 0.2f * lowcl);
    float ug = rec * sel * agree * (1.f - anchor);
    float res = 0.15f * scal[3] * ug * (f - p);
    prop[row * CC + lane] = fmaxf(anchor * s + (1.f - anchor) * p + res, 0.f);
}

// ---------------- launcher ----------------

extern "C" void kernel_launch(void* const* d_in, const int* in_sizes, int n_in,
                              void* d_out, int out_size, void* d_ws, size_t ws_size,
                              hipStream_t stream) {
    const float* logits = (const float*)d_in[0];
    const float* ew = (const float*)d_in[1];
    const float* sf = (const float*)d_in[2];
    const int* esrc = (const int*)d_in[3];
    const int* edst = (const int*)d_in[4];
    float* out = (float*)d_out;
    int E = in_sizes[1];

    float* ws = (float*)d_ws;
    float* seed = ws;                        // N*C
    float* prop = seed + NN * CC;            // N*C
    int2* edge_pk = (int2*)(prop + NN * CC); // E int2 (8B-aligned: offset is even #floats)
    float* fbase = (float*)(edge_pk + E);
    float* massA = fbase;                    // N
    float* certA = massA + NN;               // N
    float* confA = certA + NN;               // N
    float* sgA = confA + NN;                 // N
    float* denA = sgA + NN;                  // N
    float* bqA = denA + NN;                  // N
    float* scal = bqA + NN;                  // 8
    float* gp = scal + 8;                    // 64
    int* count = (int*)(gp + 64);            // N
    int* cursor = count + NN;                // N
    int* row_start = cursor + NN;            // N+1
    int* bsum = row_start + NN + 1;          // NSB
    int* boff = bsum + NSB;                  // NSB
    float* num = out;                        // d_out doubles as num until the final pass

    hipMemsetAsync(scal, 0, (8 + 64) * sizeof(float), stream);
    hipMemsetAsync(count, 0, NN * sizeof(int), stream);

    const int redBlocks = 1024;
    const int rowBlocks = (NN + 3) / 4;
    const int edgeBlocks = 1024;

    // prologue (row-wise) + CSR build
    k_seed<<<redBlocks, 256, 0, stream>>>(logits, sf, seed, prop, massA, certA, scal);
    k_conf<<<redBlocks, 256, 0, stream>>>(seed, massA, certA, confA, sgA, scal, gp);
    k_finalize<<<1, 64, 0, stream>>>(scal, gp);

    k_hist<<<edgeBlocks, 256, 0, stream>>>(edst, count, E);
    k_bsum<<<NSB, 256, 0, stream>>>(count, bsum);
    k_boff<<<1, 1, 0, stream>>>(bsum, boff, row_start);
    k_scanwrite<<<NSB, 256, 0, stream>>>(count, boff, row_start, cursor);
    k_scatter<<<edgeBlocks, 256, 0, stream>>>(esrc, edst, ew, cursor, edge_pk, E);

    // base pass: base_ctx + local_den + base quality
    k_csr<0><<<rowBlocks, 256, 0, stream>>>(edge_pk, row_start, seed, sgA, seed, sf,
                                            denA, bqA, nullptr, nullptr, nullptr);

    // 3 propagation steps
    for (int t = 0; t < 3; ++t) {
        k_csr<1><<<rowBlocks, 256, 0, stream>>>(edge_pk, row_start, prop, sgA, seed, sf,
                                                nullptr, nullptr, num, nullptr, nullptr);
        k_update<<<rowBlocks, 256, 0, stream>>>(num, denA, gp, confA, sf, seed, prop, scal);
    }

    // final pass: prop_ctx + quality + accept + blend -> out
    k_csr<2><<<rowBlocks, 256, 0, stream>>>(edge_pk, row_start, prop, sgA, seed, sf,
                                            nullptr, nullptr, nullptr, bqA, out);
}

// Round 5
// 632.299 us; speedup vs baseline: 3.4596x; 1.5325x over previous
//
#include <hip/hip_runtime.h>
#include <math.h>

#define NN 100000
#define CC 64
#define EPSF 1e-8f
#define LOG_C 4.1588830833596715f
#define SCAN_BS 1024
#define NSB ((NN + SCAN_BS - 1) / SCAN_BS)

__device__ __forceinline__ float waveSum(float v) {
#pragma unroll
    for (int off = 32; off; off >>= 1) v += __shfl_xor(v, off);
    return v;
}
// reduce across the 16 lanes of a 16-lane group (bits 0..3 of lane id)
__device__ __forceinline__ float redChanSum(float v) {
#pragma unroll
    for (int off = 8; off; off >>= 1) v += __shfl_xor(v, off);
    return v;
}
__device__ __forceinline__ float redChanMax(float v) {
#pragma unroll
    for (int off = 8; off; off >>= 1) v = fmaxf(v, __shfl_xor(v, off));
    return v;
}
// reduce across the 4 groups (bits 4..5 of lane id)
__device__ __forceinline__ float redGrpSum(float v) {
    v += __shfl_xor(v, 16);
    v += __shfl_xor(v, 32);
    return v;
}
__device__ __forceinline__ float clip01(float v) { return fminf(fmaxf(v, 0.f), 1.f); }
__device__ __forceinline__ float sigmoidf(float x) { return 1.f / (1.f + expf(-x)); }

// ---------------- row-wise prologue kernels ----------------

__global__ void k_seed(const float* __restrict__ logits, const float* __restrict__ sf,
                       float* __restrict__ seed, float* __restrict__ prop,
                       float* __restrict__ mass, float* __restrict__ cert,
                       float* __restrict__ scal) {
    int lane = threadIdx.x & 63;
    int wid = threadIdx.x >> 6;
    float accm = 0.f, accc = 0.f;
    for (int row = blockIdx.x * 4 + wid; row < NN; row += gridDim.x * 4) {
        float l = logits[row * CC + lane];
        float s = fmaxf(l, 0.f);
        seed[row * CC + lane] = s;
        prop[row * CC + lane] = s;
        float m = waveSum(s);
        float nrm = s / (m + EPSF);
        float ent = waveSum(-nrm * logf(nrm + EPSF));
        if (lane == 0) {
            mass[row] = m;
            cert[row] = 1.f - ent / LOG_C;
            accm += m;
            accc += sf[row * 2 + 1];
        }
    }
    __shared__ float sm[8];
    if (lane == 0) { sm[wid] = accm; sm[4 + wid] = accc; }
    __syncthreads();
    if (threadIdx.x == 0) {
        atomicAdd(&scal[0], sm[0] + sm[1] + sm[2] + sm[3]);
        atomicAdd(&scal[1], sm[4] + sm[5] + sm[6] + sm[7]);
    }
}

__global__ void k_conf(const float* __restrict__ seed, const float* __restrict__ mass,
                       const float* __restrict__ cert, float* __restrict__ conf,
                       float* __restrict__ sg, float* __restrict__ scal,
                       float* __restrict__ gp) {
    int lane = threadIdx.x & 63;
    int wid = threadIdx.x >> 6;
    float msc = fmaxf(scal[0] * (1.f / NN), EPSF);
    float accgp = 0.f, accconf = 0.f;
    for (int row = blockIdx.x * 4 + wid; row < NN; row += gridDim.x * 4) {
        float m = mass[row], ct = cert[row];
        float cf = clip01(0.5f * ct + 0.5f * tanhf(m / msc));
        accgp += cf * seed[row * CC + lane];
        if (lane == 0) {
            conf[row] = cf;
            sg[row] = sigmoidf(8.f * (cf - 0.55f));
            accconf += cf;
        }
    }
    __shared__ float sgp[256];
    __shared__ float scf[4];
    sgp[threadIdx.x] = accgp;
    if (lane == 0) scf[wid] = accconf;
    __syncthreads();
    if (threadIdx.x < 64)
        atomicAdd(&gp[lane], sgp[lane] + sgp[64 + lane] + sgp[128 + lane] + sgp[192 + lane]);
    if (threadIdx.x == 0) atomicAdd(&scal[2], scf[0] + scf[1] + scf[2] + scf[3]);
}

__global__ void k_finalize(float* __restrict__ scal, float* __restrict__ gp) {
    float sc = fmaxf(scal[2], EPSF);
    gp[threadIdx.x] = gp[threadIdx.x] / sc;
    if (threadIdx.x == 0) {
        scal[3] = fminf(fmaxf(1.f - scal[1] * (1.f / NN), 0.2f), 1.f);
    }
}

// ---------------- CSR build ----------------

__global__ void k_hist(const int* __restrict__ dst, int* __restrict__ count, int E) {
    int i = blockIdx.x * blockDim.x + threadIdx.x;
    int stride = gridDim.x * blockDim.x;
    for (; i < E; i += stride) atomicAdd(&count[dst[i]], 1);
}

__global__ void k_bsum(const int* __restrict__ count, int* __restrict__ bsum) {
    int b = blockIdx.x, t = threadIdx.x;
    int base = b * SCAN_BS + t * 4;
    int s = 0;
#pragma unroll
    for (int k = 0; k < 4; ++k) {
        int i = base + k;
        if (i < NN) s += count[i];
    }
#pragma unroll
    for (int off = 32; off; off >>= 1) s += __shfl_xor(s, off);
    __shared__ int red[4];
    if ((t & 63) == 0) red[t >> 6] = s;
    __syncthreads();
    if (t == 0) bsum[b] = red[0] + red[1] + red[2] + red[3];
}

__global__ void k_boff(const int* __restrict__ bsum, int* __restrict__ boff,
                       int* __restrict__ row_start) {
    int acc = 0;
    for (int i = 0; i < NSB; ++i) { boff[i] = acc; acc += bsum[i]; }
    row_start[NN] = acc;  // == E
}

__global__ void k_scanwrite(const int* __restrict__ count, const int* __restrict__ boff,
                            int* __restrict__ row_start, int* __restrict__ cursor) {
    int b = blockIdx.x, t = threadIdx.x, lane = t & 63, wid = t >> 6;
    int base = b * SCAN_BS + t * 4;
    int c0 = 0, c1 = 0, c2 = 0, c3 = 0;
    if (base < NN) c0 = count[base];
    if (base + 1 < NN) c1 = count[base + 1];
    if (base + 2 < NN) c2 = count[base + 2];
    if (base + 3 < NN) c3 = count[base + 3];
    int s = c0 + c1 + c2 + c3;
    int incl = s;
#pragma unroll
    for (int off = 1; off < 64; off <<= 1) {
        int o = __shfl_up(incl, off);
        if (lane >= off) incl += o;
    }
    __shared__ int wsum[4];
    if (lane == 63) wsum[wid] = incl;
    __syncthreads();
    int woff = 0;
    for (int i = 0; i < wid; ++i) woff += wsum[i];
    int excl = boff[b] + woff + incl - s;
    if (base < NN) { row_start[base] = excl; cursor[base] = excl; excl += c0; }
    if (base + 1 < NN) { row_start[base + 1] = excl; cursor[base + 1] = excl; excl += c1; }
    if (base + 2 < NN) { row_start[base + 2] = excl; cursor[base + 2] = excl; excl += c2; }
    if (base + 3 < NN) { row_start[base + 3] = excl; cursor[base + 3] = excl; excl += c3; }
}

__global__ void k_scatter(const int* __restrict__ src, const int* __restrict__ dst,
                          const float* __restrict__ w, int* __restrict__ cursor,
                          int2* __restrict__ edge_pk, int E) {
    int i = blockIdx.x * blockDim.x + threadIdx.x;
    int stride = gridDim.x * blockDim.x;
    for (; i < E; i += stride) {
        int d = dst[i];
        int pos = atomicAdd(&cursor[d], 1);
        edge_pk[pos] = make_int2(src[i], __float_as_int(w[i]));
    }
}

// ---------------- CSR SPMM: one wave per row, 16 lanes x 4 channels ---------
// Lane layout: grp = lane>>4 (edge slot), cidx = lane&15 (channel quad).
// MODE 0: ctx=sum w*seed[src]; num=sum (w*sg)*seed[src]; den=sum w*sg;
//         epilogue base quality -> bq, write num.
// MODE 1: num = sum (w*sg[src])*prop[src] -> numo.
// MODE 2: ctx = sum w*prop[src]; epilogue quality + accept + blend -> out.

template <int MODE>
__global__ __launch_bounds__(256) void k_csr(
    const int2* __restrict__ edge_pk, const int* __restrict__ row_start,
    const float* __restrict__ x, const float* __restrict__ sg,
    const float* __restrict__ seed, const float* __restrict__ sf,
    float* __restrict__ den, float* __restrict__ bq,
    float* __restrict__ numo, const float* __restrict__ baseq,
    float* __restrict__ outp) {
    int lane = threadIdx.x & 63;
    int row = blockIdx.x * 4 + (threadIdx.x >> 6);
    if (row >= NN) return;
    int grp = lane >> 4, cidx = lane & 15;
    int rs = row_start[row], re = row_start[row + 1];

    float4 acc = make_float4(0.f, 0.f, 0.f, 0.f);
    float4 accn = make_float4(0.f, 0.f, 0.f, 0.f);
    float accden = 0.f;

    for (int base = rs; base < re; base += 8) {
        int e0 = base + grp;
        int e1 = base + 4 + grp;
        int2 pk0 = make_int2(0, 0), pk1 = make_int2(0, 0);
        if (e0 < re) pk0 = edge_pk[e0];
        if (e1 < re) pk1 = edge_pk[e1];
        float w0 = __int_as_float(pk0.y);
        float w1 = __int_as_float(pk1.y);
        const float4 xv0 = *(const float4*)(x + pk0.x * CC + cidx * 4);
        const float4 xv1 = *(const float4*)(x + pk1.x * CC + cidx * 4);
        if (MODE == 0) {
            float ws0 = w0 * sg[pk0.x];
            float ws1 = w1 * sg[pk1.x];
            acc.x += w0 * xv0.x + w1 * xv1.x;
            acc.y += w0 * xv0.y + w1 * xv1.y;
            acc.z += w0 * xv0.z + w1 * xv1.z;
            acc.w += w0 * xv0.w + w1 * xv1.w;
            accn.x += ws0 * xv0.x + ws1 * xv1.x;
            accn.y += ws0 * xv0.y + ws1 * xv1.y;
            accn.z += ws0 * xv0.z + ws1 * xv1.z;
            accn.w += ws0 * xv0.w + ws1 * xv1.w;
            accden += ws0 + ws1;  // identical across the 16 lanes of a group
        } else if (MODE == 1) {
            float ws0 = w0 * sg[pk0.x];
            float ws1 = w1 * sg[pk1.x];
            acc.x += ws0 * xv0.x + ws1 * xv1.x;
            acc.y += ws0 * xv0.y + ws1 * xv1.y;
            acc.z += ws0 * xv0.z + ws1 * xv1.z;
            acc.w += ws0 * xv0.w + ws1 * xv1.w;
        } else {
            acc.x += w0 * xv0.x + w1 * xv1.x;
            acc.y += w0 * xv0.y + w1 * xv1.y;
            acc.z += w0 * xv0.z + w1 * xv1.z;
            acc.w += w0 * xv0.w + w1 * xv1.w;
        }
    }

    // sum partial accumulators across the 4 groups (replicates result everywhere)
    acc.x = redGrpSum(acc.x); acc.y = redGrpSum(acc.y);
    acc.z = redGrpSum(acc.z); acc.w = redGrpSum(acc.w);

    if (MODE == 1) {
        if (grp == 0) *(float4*)(numo + row * CC + cidx * 4) = acc;
        return;
    }

    // quality epilogue on (s = seed row for MODE0, prop row for MODE2; c = acc)
    const float4 s4 = *(const float4*)(((MODE == 0) ? seed : x) + row * CC + cidx * 4);
    float dot = s4.x * acc.x + s4.y * acc.y + s4.z * acc.z + s4.w * acc.w;
    float ss = s4.x * s4.x + s4.y * s4.y + s4.z * s4.z + s4.w * s4.w;
    float cc2 = acc.x * acc.x + acc.y * acc.y + acc.z * acc.z + acc.w * acc.w;
    float m = s4.x + s4.y + s4.z + s4.w;
    dot = redChanSum(dot);
    ss = redChanSum(ss);
    cc2 = redChanSum(cc2);
    m = redChanSum(m);
    float cosv = dot / (fmaxf(sqrtf(ss), 1e-8f) * fmaxf(sqrtf(cc2), 1e-8f));
    float lq = clip01((cosv + 1.f) * 0.5f);
    float inv = 1.f / (m + EPSF);
    float p0 = s4.x * inv, p1 = s4.y * inv, p2 = s4.z * inv, p3 = s4.w * inv;
    float m1 = redChanMax(fmaxf(fmaxf(p0, p1), fmaxf(p2, p3)));
    // count of max instances + max of strictly-smaller values
    float cnt = (p0 == m1) + (p1 == m1) + (p2 == m1) + (p3 == m1);
    float mlt = -3.4e38f;
    mlt = fmaxf(mlt, (p0 < m1) ? p0 : -3.4e38f);
    mlt = fmaxf(mlt, (p1 < m1) ? p1 : -3.4e38f);
    mlt = fmaxf(mlt, (p2 < m1) ? p2 : -3.4e38f);
    mlt = fmaxf(mlt, (p3 < m1) ? p3 : -3.4e38f);
    cnt = redChanSum(cnt);
    mlt = redChanMax(mlt);
    float m2 = (cnt >= 2.f) ? m1 : mlt;
    float q = 0.7f * lq + 0.2f * (m1 - m2) + 0.1f * sf[row * 2 + 1];

    if (MODE == 0) {
        accn.x = redGrpSum(accn.x); accn.y = redGrpSum(accn.y);
        accn.z = redGrpSum(accn.z); accn.w = redGrpSum(accn.w);
        float dsum = accden;
        dsum += __shfl_xor(dsum, 16);
        dsum += __shfl_xor(dsum, 32);
        if (grp == 0) *(float4*)(numo + row * CC + cidx * 4) = accn;
        if (lane == 0) {
            den[row] = dsum;
            bq[row] = q;
        }
    } else {  // MODE 2
        float accp = sigmoidf(12.f * (q - baseq[row]));
        const float4 sd = *(const float4*)(seed + row * CC + cidx * 4);
        if (grp == 0) {
            float4 o;
            o.x = accp * s4.x + (1.f - accp) * sd.x;
            o.y = accp * s4.y + (1.f - accp) * sd.y;
            o.z = accp * s4.z + (1.f - accp) * sd.z;
            o.w = accp * s4.w + (1.f - accp) * sd.w;
            *(float4*)(outp + row * CC + cidx * 4) = o;
        }
    }
}

// ---------------- propagation update: 16 lanes per row, 16 rows per block ----

__global__ __launch_bounds__(256) void k_update(
    const float* __restrict__ num, const float* __restrict__ den,
    const float* __restrict__ gp, const float* __restrict__ conf,
    const float* __restrict__ sf, const float* __restrict__ seed,
    float* __restrict__ prop, const float* __restrict__ scal) {
    int cidx = threadIdx.x & 15;
    int row = blockIdx.x * 16 + (threadIdx.x >> 4);
    if (row >= NN) return;
    float dn = fmaxf(den[row], EPSF);
    float inv = 1.f / dn;
    const float4 n4 = *(const float4*)(num + row * CC + cidx * 4);
    const float4 g4 = *(const float4*)(gp + cidx * 4);
    const float4 p4 = *(const float4*)(prop + row * CC + cidx * 4);
    const float4 s4 = *(const float4*)(seed + row * CC + cidx * 4);
    float4 f4;
    f4.x = 0.95f * (n4.x * inv) + 0.05f * g4.x;
    f4.y = 0.95f * (n4.y * inv) + 0.05f * g4.y;
    f4.z = 0.95f * (n4.z * inv) + 0.05f * g4.z;
    f4.w = 0.95f * (n4.w * inv) + 0.05f * g4.w;
    float pf = p4.x * f4.x + p4.y * f4.y + p4.z * f4.z + p4.w * f4.w;
    float pp = p4.x * p4.x + p4.y * p4.y + p4.z * p4.z + p4.w * p4.w;
    float ff = f4.x * f4.x + f4.y * f4.y + f4.z * f4.z + f4.w * f4.w;
    float sfv = s4.x * f4.x + s4.y * f4.y + s4.z * f4.z + s4.w * f4.w;
    float ss = s4.x * s4.x + s4.y * s4.y + s4.z * s4.z + s4.w * s4.w;
    pf = redChanSum(pf);
    pp = redChanSum(pp);
    ff = redChanSum(ff);
    sfv = redChanSum(sfv);
    ss = redChanSum(ss);
    float nf = fmaxf(sqrtf(ff), 1e-8f);
    float agree = clip01((pf / (fmaxf(sqrtf(pp), 1e-8f) * nf) + 1.f) * 0.5f);
    float sagree = clip01((sfv / (fmaxf(sqrtf(ss), 1e-8f) * nf) + 1.f) * 0.5f);
    float cf = conf[row];
    float anchor = fminf(fmaxf(0.6f + 0.2f * cf, 0.f), 0.995f);
    float unc = 1.f - cf;
    float lowdeg = clip01(1.f - sf[row * 2 + 0]);
    float lowcl = clip01(1.f - sf[row * 2 + 1]);
    float rec = sigmoidf(8.f * (0.5f - cf));
    float sel = clip01(unc + 0.25f * lowdeg + 0.2f * sagree + 0.2f * lowcl);
    float ug = rec * sel * agree * (1.f - anchor);
    float rsc = 0.15f * scal[3] * ug;
    float4 o;
    o.x = fmaxf(anchor * s4.x + (1.f - anchor) * p4.x + rsc * (f4.x - p4.x), 0.f);
    o.y = fmaxf(anchor * s4.y + (1.f - anchor) * p4.y + rsc * (f4.y - p4.y), 0.f);
    o.z = fmaxf(anchor * s4.z + (1.f - anchor) * p4.z + rsc * (f4.z - p4.z), 0.f);
    o.w = fmaxf(anchor * s4.w + (1.f - anchor) * p4.w + rsc * (f4.w - p4.w), 0.f);
    *(float4*)(prop + row * CC + cidx * 4) = o;
}

// ---------------- launcher ----------------

extern "C" void kernel_launch(void* const* d_in, const int* in_sizes, int n_in,
                              void* d_out, int out_size, void* d_ws, size_t ws_size,
                              hipStream_t stream) {
    const float* logits = (const float*)d_in[0];
    const float* ew = (const float*)d_in[1];
    const float* sf = (const float*)d_in[2];
    const int* esrc = (const int*)d_in[3];
    const int* edst = (const int*)d_in[4];
    float* out = (float*)d_out;
    int E = in_sizes[1];

    float* ws = (float*)d_ws;
    float* seed = ws;                        // N*C
    float* prop = seed + NN * CC;            // N*C
    int2* edge_pk = (int2*)(prop + NN * CC); // E int2
    size_t foff = (size_t)2 * NN * CC + 2 * (size_t)E;
    foff = (foff + 3) & ~(size_t)3;          // 16B-align what follows
    float* fbase = ws + foff;
    float* massA = fbase;                    // N
    float* certA = massA + NN;               // N
    float* confA = certA + NN;               // N
    float* sgA = confA + NN;                 // N
    float* denA = sgA + NN;                  // N
    float* bqA = denA + NN;                  // N
    float* scal = bqA + NN;                  // 8
    float* gp = scal + 8;                    // 64 (offset stays 16B-aligned)
    int* count = (int*)(gp + 64);            // N
    int* cursor = count + NN;                // N
    int* row_start = cursor + NN;            // N+1
    int* bsum = row_start + NN + 1;          // NSB
    int* boff = bsum + NSB;                  // NSB
    float* num = out;                        // d_out doubles as num until final pass

    hipMemsetAsync(scal, 0, (8 + 64) * sizeof(float), stream);
    hipMemsetAsync(count, 0, NN * sizeof(int), stream);

    const int redBlocks = 1024;
    const int rowBlocks = (NN + 3) / 4;
    const int rowBlocks16 = (NN + 15) / 16;
    const int edgeBlocks = 1024;

    k_seed<<<redBlocks, 256, 0, stream>>>(logits, sf, seed, prop, massA, certA, scal);
    k_conf<<<redBlocks, 256, 0, stream>>>(seed, massA, certA, confA, sgA, scal, gp);
    k_finalize<<<1, 64, 0, stream>>>(scal, gp);

    k_hist<<<edgeBlocks, 256, 0, stream>>>(edst, count, E);
    k_bsum<<<NSB, 256, 0, stream>>>(count, bsum);
    k_boff<<<1, 1, 0, stream>>>(bsum, boff, row_start);
    k_scanwrite<<<NSB, 256, 0, stream>>>(count, boff, row_start, cursor);
    k_scatter<<<edgeBlocks, 256, 0, stream>>>(esrc, edst, ew, cursor, edge_pk, E);

    // fused base pass: base_ctx quality + local_den + step-0 local_num (prop==seed)
    k_csr<0><<<rowBlocks, 256, 0, stream>>>(edge_pk, row_start, seed, sgA, seed, sf,
                                            denA, bqA, num, nullptr, nullptr);
    k_update<<<rowBlocks16, 256, 0, stream>>>(num, denA, gp, confA, sf, seed, prop, scal);

    for (int t = 1; t < 3; ++t) {
        k_csr<1><<<rowBlocks, 256, 0, stream>>>(edge_pk, row_start, prop, sgA, seed, sf,
                                                nullptr, nullptr, num, nullptr, nullptr);
        k_update<<<rowBlocks16, 256, 0, stream>>>(num, denA, gp, confA, sf, seed, prop, scal);
    }

    // final pass: prop_ctx + quality + accept + blend -> out
    k_csr<2><<<rowBlocks, 256, 0, stream>>>(edge_pk, row_start, prop, sgA, seed, sf,
                                            nullptr, nullptr, nullptr, bqA, out);
}